// Round 1
// baseline (2058.844 us; speedup 1.0000x reference)
//
#include <hip/hip_runtime.h>
#include <hip/hip_bf16.h>
#include <cstdint>
#include <cstddef>

// Problem dims
#define TT 4096   // B*S tokens
#define SS 2048   // S
#define DD 1024   // D
#define DDI 2048  // DI
#define LL 6
#define VV 32000
#define AA 7

typedef __hip_bfloat16 bf16;
typedef __attribute__((ext_vector_type(8))) short bf16x8;   // 8 bf16 in 4 VGPRs
typedef __attribute__((ext_vector_type(4))) float f32x4;

typedef const __attribute__((address_space(1))) void* gas_ptr;
typedef __attribute__((address_space(3))) void* las_ptr;

static __device__ __forceinline__ float b2f(bf16 h) { return __bfloat162float(h); }
static __device__ __forceinline__ bf16 f2b(float f) { return __float2bfloat16(f); }

// ---------------------------------------------------------------------------
// Generic bf16 MFMA GEMM: C[M,N] = A[M,K] @ Wt[N,K]^T, epilogue by template.
// m97-structure: 128x128 tile, 4 waves (2x2 of 64x64), BK=32,
// global_load_lds width=16 staging, 2 barriers per K-step.
// Requires M%128==0, N%128==0, K%32==0 (all shapes here comply).
// EPI: 0=store bf16; 1=store f32 cols<ncap (u);
//      2=mul silu(z) store bf16; 3=residual f32 in/out + bf16 out;
//      4=bias+relu bf16; 5=bias f32
// ---------------------------------------------------------------------------
template<int EPI>
__global__ __launch_bounds__(256)
void gemm_k(const bf16* __restrict__ A, const bf16* __restrict__ Wt,
            int K, int out_ld,
            float* __restrict__ of32, bf16* __restrict__ ob16,
            const float* __restrict__ bias,
            const bf16* __restrict__ zp, int z_ld, int ncap)
{
    __shared__ bf16x8 lsA8[128 * 4];   // 128 rows x 32 bf16 (8 KiB)
    __shared__ bf16x8 lsB8[128 * 4];
    bf16* lsA = (bf16*)lsA8;
    bf16* lsB = (bf16*)lsB8;

    const int tid  = threadIdx.x;
    const int w    = tid >> 6;
    const int lane = tid & 63;
    const int row0 = blockIdx.x * 128;
    const int col0 = blockIdx.y * 128;
    const int wr   = (w >> 1) * 64;    // wave's 64x64 sub-tile
    const int wc   = (w & 1) * 64;
    const int l15  = lane & 15;
    const int kq   = lane >> 4;

    f32x4 acc[4][4];
#pragma unroll
    for (int m = 0; m < 4; ++m)
#pragma unroll
        for (int n = 0; n < 4; ++n) acc[m][n] = f32x4{0.f, 0.f, 0.f, 0.f};

    // staging: slot s in [0,512): tile row = s>>2, 16B quarter = s&3
    const int s0 = tid, s1 = tid + 256;
    const size_t ga0 = (size_t)(row0 + (s0 >> 2)) * K + (s0 & 3) * 8;
    const size_t ga1 = (size_t)(row0 + (s1 >> 2)) * K + (s1 & 3) * 8;
    const size_t gb0 = (size_t)(col0 + (s0 >> 2)) * K + (s0 & 3) * 8;
    const size_t gb1 = (size_t)(col0 + (s1 >> 2)) * K + (s1 & 3) * 8;
    // wave-uniform LDS bases (HW writes lane l at base + l*16B)
    bf16* la0 = lsA + (size_t)(w * 64) * 8;
    bf16* la1 = lsA + (size_t)(256 + w * 64) * 8;
    bf16* lb0 = lsB + (size_t)(w * 64) * 8;
    bf16* lb1 = lsB + (size_t)(256 + w * 64) * 8;

    for (int k0 = 0; k0 < K; k0 += 32) {
        __builtin_amdgcn_global_load_lds((gas_ptr)(A  + ga0 + k0), (las_ptr)la0, 16, 0, 0);
        __builtin_amdgcn_global_load_lds((gas_ptr)(A  + ga1 + k0), (las_ptr)la1, 16, 0, 0);
        __builtin_amdgcn_global_load_lds((gas_ptr)(Wt + gb0 + k0), (las_ptr)lb0, 16, 0, 0);
        __builtin_amdgcn_global_load_lds((gas_ptr)(Wt + gb1 + k0), (las_ptr)lb1, 16, 0, 0);
        __syncthreads();   // vmcnt(0) drained before barrier -> staged data visible

        bf16x8 af[4], bfr[4];
#pragma unroll
        for (int m = 0; m < 4; ++m)
            af[m] = *(const bf16x8*)(lsA + (size_t)(wr + m * 16 + l15) * 32 + kq * 8);
#pragma unroll
        for (int n = 0; n < 4; ++n)
            bfr[n] = *(const bf16x8*)(lsB + (size_t)(wc + n * 16 + l15) * 32 + kq * 8);
#pragma unroll
        for (int m = 0; m < 4; ++m)
#pragma unroll
            for (int n = 0; n < 4; ++n)
                acc[m][n] = __builtin_amdgcn_mfma_f32_16x16x32_bf16(af[m], bfr[n], acc[m][n], 0, 0, 0);
        __syncthreads();   // done reading LDS before next stage overwrites
    }

    // epilogue: C/D layout col=lane&15, row=(lane>>4)*4+reg  [verified m89/m91]
#pragma unroll
    for (int m = 0; m < 4; ++m) {
#pragma unroll
        for (int n = 0; n < 4; ++n) {
#pragma unroll
            for (int r = 0; r < 4; ++r) {
                const int row = row0 + wr + m * 16 + kq * 4 + r;
                const int col = col0 + wc + n * 16 + l15;
                float v = acc[m][n][r];
                if (EPI == 0) {
                    ob16[(size_t)row * out_ld + col] = f2b(v);
                } else if (EPI == 1) {
                    if (col < ncap) of32[(size_t)row * out_ld + col] = v;
                } else if (EPI == 2) {
                    float zf = b2f(zp[(size_t)row * z_ld + col]);
                    v *= zf / (1.f + expf(-zf));
                    ob16[(size_t)row * out_ld + col] = f2b(v);
                } else if (EPI == 3) {
                    float rr = of32[(size_t)row * out_ld + col] + v;
                    of32[(size_t)row * out_ld + col] = rr;
                    ob16[(size_t)row * out_ld + col] = f2b(rr);
                } else if (EPI == 4) {
                    v = fmaxf(v + bias[col], 0.f);
                    ob16[(size_t)row * out_ld + col] = f2b(v);
                } else {
                    of32[(size_t)row * out_ld + col] = v + bias[col];
                }
            }
        }
    }
}

// ---------------------------------------------------------------------------
// fp32 [K,N] -> bf16 [N,K] transpose (64x64 tiles through LDS, pad 66 for banks)
// ---------------------------------------------------------------------------
__global__ __launch_bounds__(256)
void transpose_k(const float* __restrict__ W, bf16* __restrict__ WT, int K, int N)
{
    __shared__ bf16 t[64][66];
    const int k0 = blockIdx.x * 64, n0 = blockIdx.y * 64;
    const int tid = threadIdx.x;
#pragma unroll
    for (int i = 0; i < 16; ++i) {
        int idx = i * 256 + tid;
        int kk = idx >> 6, nn = idx & 63;
        t[nn][kk] = f2b(W[(size_t)(k0 + kk) * N + n0 + nn]);
    }
    __syncthreads();
#pragma unroll
    for (int i = 0; i < 16; ++i) {
        int idx = i * 256 + tid;
        int nn = idx >> 6, kk = idx & 63;
        WT[(size_t)(n0 + nn) * K + k0 + kk] = t[nn][kk];
    }
}

// B_ssm [DI,16] fp32 -> bf16 [128,DI] padded, x0.1 folded in
__global__ void prep_bm_k(const float* __restrict__ Bm, bf16* __restrict__ BmT)
{
    int idx = blockIdx.x * 256 + threadIdx.x;   // 128*2048
    int n = idx >> 11, k = idx & 2047;
    float v = (n < 16) ? Bm[(size_t)k * 16 + n] * 0.1f : 0.f;
    BmT[idx] = f2b(v);
}

// C_ssm [16,DI] fp32 -> bf16 [DI,32] padded (K padded 16->32)
__global__ void prep_cm_k(const float* __restrict__ Cm, bf16* __restrict__ CmT)
{
    int idx = blockIdx.x * 256 + threadIdx.x;   // 2048*32
    int i = idx >> 5, k = idx & 31;
    float v = (k < 16) ? Cm[(size_t)k * 2048 + i] : 0.f;
    CmT[idx] = f2b(v);
}

// features -> fp32 residual copy + bf16 copy
__global__ void copyfeat_k(const float* __restrict__ f, float* __restrict__ xf,
                           bf16* __restrict__ xb)
{
    int i = (blockIdx.x * 256 + threadIdx.x) * 4;
    float4 v = *(const float4*)(f + i);
    *(float4*)(xf + i) = v;
    xb[i + 0] = f2b(v.x);
    xb[i + 1] = f2b(v.y);
    xb[i + 2] = f2b(v.z);
    xb[i + 3] = f2b(v.w);
}

// causal depthwise conv (K=4) + bias + silu; xp = first DI cols of xz[T,4096]
__global__ void conv_k(const bf16* __restrict__ xz, const float* __restrict__ cw,
                       const float* __restrict__ cb, bf16* __restrict__ xc)
{
    int idx = blockIdx.x * 256 + threadIdx.x;   // T*DI
    int t = idx >> 11, i = idx & 2047;
    int s = t & (SS - 1);
    float4 wv = *(const float4*)(cw + i * 4);
    float acc = cb[i];
    const bf16* base = xz + (size_t)t * 4096 + i;
    if (s >= 3) {
        acc = fmaf(b2f(base[-3 * 4096]), wv.x, acc);
        acc = fmaf(b2f(base[-2 * 4096]), wv.y, acc);
        acc = fmaf(b2f(base[-1 * 4096]), wv.z, acc);
    } else {
        if (s >= 2) acc = fmaf(b2f(base[-2 * 4096]), wv.y, acc);
        if (s >= 1) acc = fmaf(b2f(base[-1 * 4096]), wv.z, acc);
    }
    acc = fmaf(b2f(base[0]), wv.w, acc);
    float sig = 1.f / (1.f + expf(-acc));
    xc[idx] = f2b(acc * sig);
}

// chunked parallel scan: h_t = 0.9 h_{t-1} + u_t, per (batch, n).
// block = one batch; threads = 16 chunks x 16 n; 128 steps/chunk.
// writes hs [T,32] bf16 with cols 16..31 zeroed (K-pad for the Cm GEMM).
__global__ void scan_k(const float* __restrict__ u, bf16* __restrict__ hs)
{
    const float APOW = 1.390083e-06f;   // 0.9^128
    int b = blockIdx.x;
    int tid = threadIdx.x;
    int c = tid >> 4, n = tid & 15;
    const float* ub = u + (size_t)b * SS * 16;
    bf16* hb = hs + (size_t)b * SS * 32;
    int sbase = c * 128;

    float h = 0.f;
    for (int s = 0; s < 128; ++s) h = 0.9f * h + ub[(size_t)(sbase + s) * 16 + n];

    __shared__ float carry[16][16];
    carry[c][n] = h;
    __syncthreads();

    float H = 0.f;                       // state entering this chunk
    for (int j = 0; j < c; ++j) H = H * APOW + carry[j][n];

    const bf16 zero = f2b(0.f);
    h = H;
    for (int s = 0; s < 128; ++s) {
        h = 0.9f * h + ub[(size_t)(sbase + s) * 16 + n];
        hb[(size_t)(sbase + s) * 32 + n] = f2b(h);
        hb[(size_t)(sbase + s) * 32 + 16 + n] = zero;
    }
}

// LayerNorm fp32 -> bf16
__global__ __launch_bounds__(256)
void ln_k(const float* __restrict__ x, const float* __restrict__ g,
          const float* __restrict__ bb, bf16* __restrict__ xn)
{
    int t = blockIdx.x, tid = threadIdx.x;
    const float* xr = x + (size_t)t * DD;
    float4 v = *(const float4*)(xr + tid * 4);
    float s = v.x + v.y + v.z + v.w;
#pragma unroll
    for (int o = 32; o > 0; o >>= 1) s += __shfl_down(s, o, 64);
    __shared__ float r1[4], r2[4];
    if ((tid & 63) == 0) r1[tid >> 6] = s;
    __syncthreads();
    float mu = (r1[0] + r1[1] + r1[2] + r1[3]) * (1.f / DD);
    float d0 = v.x - mu, d1 = v.y - mu, d2 = v.z - mu, d3 = v.w - mu;
    float ss = d0 * d0 + d1 * d1 + d2 * d2 + d3 * d3;
#pragma unroll
    for (int o = 32; o > 0; o >>= 1) ss += __shfl_down(ss, o, 64);
    if ((tid & 63) == 0) r2[tid >> 6] = ss;
    __syncthreads();
    float var = (r2[0] + r2[1] + r2[2] + r2[3]) * (1.f / DD);
    float inv = rsqrtf(var + 1e-5f);
    int di = tid * 4;
    xn[(size_t)t * DD + di + 0] = f2b(d0 * inv * g[di + 0] + bb[di + 0]);
    xn[(size_t)t * DD + di + 1] = f2b(d1 * inv * g[di + 1] + bb[di + 1]);
    xn[(size_t)t * DD + di + 2] = f2b(d2 * inv * g[di + 2] + bb[di + 2]);
    xn[(size_t)t * DD + di + 3] = f2b(d3 * inv * g[di + 3] + bb[di + 3]);
}

// tiny head: actions = tanh(h2 @ w3 + b3), w3 [256,7] fp32
__global__ void act3_k(const bf16* __restrict__ h2, const float* __restrict__ w3,
                       const float* __restrict__ b3, float* __restrict__ out)
{
    int idx = blockIdx.x * 256 + threadIdx.x;
    if (idx >= TT * AA) return;
    int t = idx / AA, a = idx - t * AA;
    float acc = b3[a];
    const bf16* hr = h2 + (size_t)t * 256;
    for (int k = 0; k < 256; ++k)
        acc = fmaf(b2f(hr[k]), w3[k * AA + a], acc);
    out[idx] = tanhf(acc);
}

// ---------------------------------------------------------------------------
extern "C" void kernel_launch(void* const* d_in, const int* in_sizes, int n_in,
                              void* d_out, int out_size, void* d_ws, size_t ws_size,
                              hipStream_t stream)
{
    (void)in_sizes; (void)n_in; (void)out_size; (void)ws_size;
    const float* features = (const float*)d_in[0];
    const float* in_proj_w = (const float*)d_in[1];
    const float* conv_w = (const float*)d_in[2];
    const float* conv_b = (const float*)d_in[3];
    const float* B_ssm = (const float*)d_in[4];
    const float* C_ssm = (const float*)d_in[5];
    const float* out_w = (const float*)d_in[6];
    const float* ln_g = (const float*)d_in[7];
    const float* ln_b = (const float*)d_in[8];
    const float* act_w1 = (const float*)d_in[9];
    const float* act_b1 = (const float*)d_in[10];
    const float* act_w2 = (const float*)d_in[11];
    const float* act_b2 = (const float*)d_in[12];
    const float* act_w3 = (const float*)d_in[13];
    const float* act_b3 = (const float*)d_in[14];
    const float* lang_w1 = (const float*)d_in[15];
    const float* lang_b1 = (const float*)d_in[16];
    const float* lang_w2 = (const float*)d_in[17];
    const float* lang_b2 = (const float*)d_in[18];

    char* p = (char*)d_ws;
    size_t off = 0;
    auto alloc = [&](size_t bytes) -> void* {
        void* q = p + off;
        off = (off + bytes + 255) & ~(size_t)255;
        return q;
    };
    float* x_f  = (float*)alloc((size_t)TT * DD * 4);     // fp32 residual stream
    bf16*  x_b  = (bf16*) alloc((size_t)TT * DD * 2);     // bf16 mirror
    bf16*  xz   = (bf16*) alloc((size_t)TT * 4096 * 2);   // in_proj out (xp|z)
    bf16*  xc   = (bf16*) alloc((size_t)TT * DDI * 2);    // conv out; later reused as y
    float* u    = (float*)alloc((size_t)TT * 16 * 4);
    bf16*  hs   = (bf16*) alloc((size_t)TT * 32 * 2);     // scan out, K-padded
    bf16*  xn   = (bf16*) alloc((size_t)TT * DD * 2);
    bf16*  h1   = (bf16*) alloc((size_t)TT * 512 * 2);
    bf16*  h2   = (bf16*) alloc((size_t)TT * 256 * 2);
    bf16*  hl   = (bf16*) alloc((size_t)TT * DD * 2);
    bf16*  inwT = (bf16*) alloc((size_t)LL * 4096 * 1024 * 2);
    bf16*  owT  = (bf16*) alloc((size_t)LL * 1024 * 2048 * 2);
    bf16*  bmT  = (bf16*) alloc((size_t)LL * 128 * 2048 * 2);
    bf16*  cmT  = (bf16*) alloc((size_t)LL * 2048 * 32 * 2);
    bf16*  a1T  = (bf16*) alloc((size_t)512 * 1024 * 2);
    bf16*  a2T  = (bf16*) alloc((size_t)256 * 512 * 2);
    bf16*  l1T  = (bf16*) alloc((size_t)1024 * 1024 * 2);
    bf16*  l2T  = (bf16*) alloc((size_t)VV * 1024 * 2);
    bf16*  y    = xc;   // xc dead once u is computed

    // ---- prep: fp32->bf16 + transpose all GEMM weights (per call) ----
    copyfeat_k<<<TT * DD / 1024, 256, 0, stream>>>(features, x_f, x_b);
    for (int l = 0; l < LL; ++l) {
        transpose_k<<<dim3(16, 64), 256, 0, stream>>>(in_proj_w + (size_t)l * 1024 * 4096,
                                                      inwT + (size_t)l * 4096 * 1024, 1024, 4096);
        transpose_k<<<dim3(32, 16), 256, 0, stream>>>(out_w + (size_t)l * 2048 * 1024,
                                                      owT + (size_t)l * 1024 * 2048, 2048, 1024);
        prep_bm_k<<<(128 * 2048) / 256, 256, 0, stream>>>(B_ssm + (size_t)l * 2048 * 16,
                                                          bmT + (size_t)l * 128 * 2048);
        prep_cm_k<<<(2048 * 32) / 256, 256, 0, stream>>>(C_ssm + (size_t)l * 16 * 2048,
                                                         cmT + (size_t)l * 2048 * 32);
    }
    transpose_k<<<dim3(16, 8), 256, 0, stream>>>(act_w1, a1T, 1024, 512);
    transpose_k<<<dim3(8, 4), 256, 0, stream>>>(act_w2, a2T, 512, 256);
    transpose_k<<<dim3(16, 16), 256, 0, stream>>>(lang_w1, l1T, 1024, 1024);
    transpose_k<<<dim3(16, 500), 256, 0, stream>>>(lang_w2, l2T, 1024, VV);

    // ---- 6 mamba blocks ----
    for (int l = 0; l < LL; ++l) {
        // xz = x @ in_w
        gemm_k<0><<<dim3(32, 32), 256, 0, stream>>>(x_b, inwT + (size_t)l * 4096 * 1024,
                                                    1024, 4096, nullptr, xz, nullptr, nullptr, 0, 0);
        // xc = silu(causal_dwconv(xp) + cb)
        conv_k<<<TT * DDI / 256, 256, 0, stream>>>(xz, conv_w + (size_t)l * DDI * 4,
                                                   conv_b + (size_t)l * DDI, xc);
        // u = xc @ (Bm*0.1)  (N padded to 128, store cols<16)
        gemm_k<1><<<dim3(32, 1), 256, 0, stream>>>(xc, bmT + (size_t)l * 128 * 2048,
                                                   2048, 16, u, nullptr, nullptr, nullptr, 0, 16);
        // hs = scan(u)
        scan_k<<<2, 256, 0, stream>>>(u, hs);
        // y = (hs @ Cm) * silu(z)
        gemm_k<2><<<dim3(32, 16), 256, 0, stream>>>(hs, cmT + (size_t)l * 2048 * 32,
                                                    32, 2048, nullptr, y, nullptr, xz + 2048, 4096, 0);
        // x += y @ ow  (fp32 residual, refresh bf16 mirror)
        gemm_k<3><<<dim3(32, 8), 256, 0, stream>>>(y, owT + (size_t)l * 1024 * 2048,
                                                   2048, 1024, x_f, x_b, nullptr, nullptr, 0, 0);
    }

    // ---- LN + heads ----
    ln_k<<<TT, 256, 0, stream>>>(x_f, ln_g, ln_b, xn);
    gemm_k<4><<<dim3(32, 4), 256, 0, stream>>>(xn, a1T, 1024, 512, nullptr, h1, act_b1, nullptr, 0, 0);
    gemm_k<4><<<dim3(32, 2), 256, 0, stream>>>(h1, a2T, 512, 256, nullptr, h2, act_b2, nullptr, 0, 0);
    act3_k<<<(TT * AA + 255) / 256, 256, 0, stream>>>(h2, act_w3, act_b3, (float*)d_out);
    gemm_k<4><<<dim3(32, 8), 256, 0, stream>>>(xn, l1T, 1024, 1024, nullptr, hl, lang_b1, nullptr, 0, 0);
    gemm_k<5><<<dim3(32, 250), 256, 0, stream>>>(hl, l2T, 1024, VV,
                                                 (float*)d_out + (size_t)TT * AA, nullptr,
                                                 lang_b2, nullptr, 0, 0);
}